// Round 5
// baseline (255.390 us; speedup 1.0000x reference)
//
#include <hip/hip_runtime.h>

// B=4, HG=WG=32 -> 1024 tokens/batch, 4096 total; D=768, NH=12, HD=64, K=7 (49 neighbors)

typedef __bf16 bf16x8 __attribute__((ext_vector_type(8)));
typedef short s16x4 __attribute__((ext_vector_type(4)));
typedef float f32x4 __attribute__((ext_vector_type(4)));

__device__ __forceinline__ unsigned short f2bf(float f) {
  unsigned u = __float_as_uint(f);
  u += 0x7fffu + ((u >> 16) & 1u);   // RNE
  return (unsigned short)(u >> 16);
}

// ---------------- fp32 -> bf16 conversion of x, qkv_w, proj_w ----------------
__global__ void cvt_kernel(const float* __restrict__ x, const float* __restrict__ w1,
                           const float* __restrict__ w2, unsigned short* __restrict__ xo,
                           unsigned short* __restrict__ w1o, unsigned short* __restrict__ w2o) {
  const int n1 = 4096 * 768 / 4;
  const int n2 = 2304 * 768 / 4;
  const int n3 = 768 * 768 / 4;
  int i = blockIdx.x * 256 + threadIdx.x;
  float4 v;
  unsigned short* dst;
  int o;
  if (i < n1) {
    o = i; v = ((const float4*)x)[o]; dst = xo;
  } else if (i < n1 + n2) {
    o = i - n1; v = ((const float4*)w1)[o]; dst = w1o;
  } else if (i < n1 + n2 + n3) {
    o = i - n1 - n2; v = ((const float4*)w2)[o]; dst = w2o;
  } else {
    return;
  }
  ushort4 r;
  r.x = f2bf(v.x); r.y = f2bf(v.y); r.z = f2bf(v.z); r.w = f2bf(v.w);
  ((ushort4*)dst)[o] = r;
}

// ---------------- bf16 GEMM, C = A * B^T + bias ----------------
// Global->VGPR prefetch pipeline: loads for tile it+1 are issued BEFORE compute(it)
// and written to LDS after the post-compute barrier -> barriers fence LDS only,
// global latency is covered by compute. Slab-K-major LDS: all ds ops conflict-free.
// Block tile: (MT*32) x (NT*32), 4 waves in 2x2; BK=64, 12 iterations.
// MODE 0 (qkv): Q cols scaled by 0.125*log2(e), token-major [h][4096][64];
//               K token-major; V TRANSPOSED vt[h][64][4096].
// MODE 1 (proj): fp32 out, row-major [M][N].
template <int MT, int NT, int MODE>
__global__ __launch_bounds__(256, 4) void gemm_bt(const unsigned short* __restrict__ A,
                                                  const unsigned short* __restrict__ Bm,
                                                  const float* __restrict__ bias,
                                                  unsigned short* __restrict__ obf,
                                                  unsigned short* __restrict__ vtout,
                                                  float* __restrict__ of32,
                                                  int N) {
  constexpr int KD = 768;
  constexpr int NITER = KD / 64;           // 12
  constexpr int AE = MT * 2048;            // LDS elems for A (MT chunks of 2048)
  constexpr int BE = NT * 2048;
  __shared__ __align__(16) unsigned short sm[AE + BE];
  const int tid = threadIdx.x, lane = tid & 63, wv = tid >> 6;
  const int lr = lane & 15, lq = lane >> 4;
  const int m0 = blockIdx.y * (MT * 32);
  const int n0 = blockIdx.x * (NT * 32);

  // staging: thread t stages 16B per chunk; chunk j covers slabs {2j, 2j+1}
  // flat f = j*256+t -> row=(f>>7)*16+(f&15), k-off=((f>>6)&1)*32+((f>>4)&3)*8
  const unsigned short* gpA[MT];
  const unsigned short* gpB[NT];
#pragma unroll
  for (int j = 0; j < MT; ++j) {
    int f = j * 256 + tid;
    gpA[j] = A + (size_t)(m0 + ((f >> 7) << 4) + (f & 15)) * KD + ((f >> 6) & 1) * 32 + ((f >> 4) & 3) * 8;
  }
#pragma unroll
  for (int j = 0; j < NT; ++j) {
    int f = j * 256 + tid;
    gpB[j] = Bm + (size_t)(n0 + ((f >> 7) << 4) + (f & 15)) * KD + ((f >> 6) & 1) * 32 + ((f >> 4) & 3) * 8;
  }
  unsigned short* wA = sm + tid * 8;
  unsigned short* wB = sm + AE + tid * 8;

  uint4 rA[MT], rB[NT];
  auto gload = [&](int k0) {
#pragma unroll
    for (int j = 0; j < MT; ++j) rA[j] = *(const uint4*)(gpA[j] + k0);
#pragma unroll
    for (int j = 0; j < NT; ++j) rB[j] = *(const uint4*)(gpB[j] + k0);
  };
  auto dswrite = [&]() {
#pragma unroll
    for (int j = 0; j < MT; ++j) *(uint4*)(wA + j * 2048) = rA[j];
#pragma unroll
    for (int j = 0; j < NT; ++j) *(uint4*)(wB + j * 2048) = rB[j];
  };

  f32x4 acc[MT][NT] = {};
  gload(0);
  dswrite();
#pragma unroll
  for (int it = 0; it < NITER; ++it) {
    __syncthreads();                          // publishes tile it (LDS-only wait)
    if (it + 1 < NITER) gload((it + 1) * 64); // in flight during compute
#pragma unroll
    for (int c = 0; c < 2; ++c) {
      bf16x8 af[MT], bfb[NT];
#pragma unroll
      for (int im = 0; im < MT; ++im)
        af[im] = *(const bf16x8*)(sm + ((wv >> 1) * MT + im) * 1024 + c * 512 + lq * 128 + lr * 8);
#pragma unroll
      for (int in = 0; in < NT; ++in)
        bfb[in] = *(const bf16x8*)(sm + AE + ((wv & 1) * NT + in) * 1024 + c * 512 + lq * 128 + lr * 8);
#pragma unroll
      for (int im = 0; im < MT; ++im)
#pragma unroll
        for (int in = 0; in < NT; ++in)
          acc[im][in] = __builtin_amdgcn_mfma_f32_16x16x32_bf16(af[im], bfb[in], acc[im][in], 0, 0, 0);
    }
    __syncthreads();                          // tile it fully consumed (LDS-only wait)
    if (it + 1 < NITER) dswrite();            // loads drained here, latency covered
  }

  const int mw = m0 + (wv >> 1) * (MT * 16);
  const int nw = n0 + (wv & 1) * (NT * 16);
#pragma unroll
  for (int im = 0; im < MT; ++im) {
#pragma unroll
    for (int in = 0; in < NT; ++in) {
      int gn = nw + in * 16 + lr;
      float bsv = bias[gn];
      if (MODE == 0) {
        int sidx = gn / 768;
        int rem = gn - sidx * 768;
        int hh = rem >> 6, dd = gn & 63;
        if (sidx == 2) {
          // V -> transposed vt[(hh*64+dd)*4096 + token]
          int gm0 = mw + im * 16 + lq * 4;
          ushort4 pk;
          pk.x = f2bf(acc[im][in][0] + bsv);
          pk.y = f2bf(acc[im][in][1] + bsv);
          pk.z = f2bf(acc[im][in][2] + bsv);
          pk.w = f2bf(acc[im][in][3] + bsv);
          *(ushort4*)(vtout + (size_t)(hh * 64 + dd) * 4096 + gm0) = pk;
        } else {
          const float scale = (sidx == 0) ? 0.18033688f : 1.0f;  // 0.125 * log2(e) for Q
#pragma unroll
          for (int r = 0; r < 4; ++r) {
            int gm = mw + im * 16 + lq * 4 + r;
            obf[((size_t)(sidx * 12 + hh) * 4096 + gm) * 64 + dd] = f2bf((acc[im][in][r] + bsv) * scale);
          }
        }
      } else {
#pragma unroll
        for (int r = 0; r < 4; ++r) {
          int gm = mw + im * 16 + lq * 4 + r;
          of32[(size_t)gm * N + gn] = acc[im][in][r] + bsv;
        }
      }
    }
  }
}

// ---------------- neighborhood attention (MFMA) ---------------- (unchanged)
__global__ __launch_bounds__(256, 2) void natten_kernel(const unsigned short* __restrict__ qkvt,
                                                        unsigned short* __restrict__ aout) {
  __shared__ __align__(16) unsigned short sQ[64 * 64];    //  8 KB
  __shared__ __align__(16) unsigned short sK[256 * 64];   // 32 KB
  __shared__ __align__(16) unsigned short sVt[64 * 256];  // 32 KB
  const int h = blockIdx.x, ip = blockIdx.y, b = blockIdx.z;
  const int i0 = ip * 2;
  const int tid = threadIdx.x, lane = tid & 63, wv = tid >> 6;
  const int lg = lane >> 4, lm = lane & 15;
  int si0 = i0 - 3; si0 = si0 < 0 ? 0 : si0; if (si0 > 25) si0 = 25;
  const int gb = b * 1024;
  const unsigned short* Qg = qkvt + ((size_t)h * 4096 + gb + i0 * 32) * 64;
  const unsigned short* Kg = qkvt + ((size_t)(12 + h) * 4096 + gb) * 64;
  const unsigned short* Vg = qkvt + (size_t)24 * 4096 * 64 + (size_t)h * 64 * 4096 + gb;

#pragma unroll
  for (int it = 0; it < 2; ++it) {  // Q: 64 q x 64 d
    int f = it * 256 + tid;
    int q = f >> 3, c16 = f & 7;
    uint4 v = *(const uint4*)(Qg + q * 64 + c16 * 8);
    int s = q & 15;
    *(uint2*)(sQ + q * 64 + ((((c16 << 1)) ^ s) << 2)) = make_uint2(v.x, v.y);
    *(uint2*)(sQ + q * 64 + ((((c16 << 1) | 1) ^ s) << 2)) = make_uint2(v.z, v.w);
  }
#pragma unroll
  for (int it = 0; it < 8; ++it) {  // K: 256 tok x 64 d
    int f = it * 256 + tid;
    int t = f >> 3, c16 = f & 7;
    int wr = t >> 5, c = t & 31;
    int row = si0 + wr; if (row > 31) row = 31;
    uint4 v = *(const uint4*)(Kg + (row * 32 + c) * 64 + c16 * 8);
    int s = t & 15;
    *(uint2*)(sK + t * 64 + ((((c16 << 1)) ^ s) << 2)) = make_uint2(v.x, v.y);
    *(uint2*)(sK + t * 64 + ((((c16 << 1) | 1) ^ s) << 2)) = make_uint2(v.z, v.w);
  }
#pragma unroll
  for (int it = 0; it < 8; ++it) {  // Vt: 64 d x 256 tok
    int f = it * 256 + tid;
    int d = f >> 5, tc16 = f & 31;
    int wr = tc16 >> 2;
    int row = si0 + wr; if (row > 31) row = 31;
    uint4 v = *(const uint4*)(Vg + (size_t)d * 4096 + row * 32 + (tc16 & 3) * 8);
    int s = d & 15;
    *(uint2*)(sVt + d * 256 + ((((tc16 << 1)) ^ s) << 2)) = make_uint2(v.x, v.y);
    *(uint2*)(sVt + d * 256 + ((((tc16 << 1) | 1) ^ s) << 2)) = make_uint2(v.z, v.w);
  }
  __syncthreads();

  const int row_sel = wv >> 1;
  const int jhalf = wv & 1;
  const int i = i0 + row_sel;
  int si_w = i - 3; si_w = si_w < 0 ? 0 : si_w; if (si_w > 25) si_w = 25;
  const int toff = (si_w - si0) * 32;
  const int j = jhalf * 16 + lm;
  int sj = j - 3; sj = sj < 0 ? 0 : sj; if (sj > 25) sj = 25;

  float madd[2][4];
#pragma unroll
  for (int p = 0; p < 2; ++p)
#pragma unroll
    for (int r = 0; r < 4; ++r) {
      int c = p * 16 + lg * 4 + r;
      madd[p][r] = (c >= sj && c <= sj + 6) ? 0.f : -1e30f;
    }

  s16x4 qf[4];
  const int qrow = row_sel * 32 + j;
#pragma unroll
  for (int ks = 0; ks < 4; ++ks)
    qf[ks] = *(const s16x4*)(sQ + qrow * 64 + ((((ks << 2) + lg) ^ (qrow & 15)) << 2));

  f32x4 accS[14];
#pragma unroll
  for (int tt = 0; tt < 14; ++tt) {
    f32x4 a = {0.f, 0.f, 0.f, 0.f};
    const int trow = toff + tt * 16 + lm;
    const unsigned short* kr = sK + trow * 64;
    const int sw = trow & 15;
#pragma unroll
    for (int ks = 0; ks < 4; ++ks) {
      s16x4 kf = *(const s16x4*)(kr + ((((ks << 2) + lg) ^ sw) << 2));
      a = __builtin_amdgcn_mfma_f32_16x16x16bf16_1k(kf, qf[ks], a, 0, 0, 0);
    }
    accS[tt] = a;
  }

  float mx = -3e38f;
#pragma unroll
  for (int tt = 0; tt < 14; ++tt)
#pragma unroll
    for (int r = 0; r < 4; ++r) {
      float v = accS[tt][r] + madd[tt & 1][r];
      accS[tt][r] = v;
      mx = fmaxf(mx, v);
    }
  mx = fmaxf(mx, __shfl_xor(mx, 16, 64));
  mx = fmaxf(mx, __shfl_xor(mx, 32, 64));
  float sum = 0.f;
#pragma unroll
  for (int tt = 0; tt < 14; ++tt)
#pragma unroll
    for (int r = 0; r < 4; ++r) {
      float p = exp2f(accS[tt][r] - mx);
      accS[tt][r] = p;
      sum += p;
    }
  sum += __shfl_xor(sum, 16, 64);
  sum += __shfl_xor(sum, 32, 64);
  const float inv = 1.f / sum;

  s16x4 pf[14];
#pragma unroll
  for (int tt = 0; tt < 14; ++tt) {
    union { unsigned u[2]; s16x4 v; } pk;
    pk.u[0] = ((unsigned)f2bf(accS[tt][1]) << 16) | f2bf(accS[tt][0]);
    pk.u[1] = ((unsigned)f2bf(accS[tt][3]) << 16) | f2bf(accS[tt][2]);
    pf[tt] = pk.v;
  }

  f32x4 accO[4] = {};
  const int choff = toff >> 2;
#pragma unroll
  for (int tt = 0; tt < 14; ++tt) {
    const int c8 = choff + tt * 4 + lg;
#pragma unroll
    for (int nt = 0; nt < 4; ++nt) {
      const int d = nt * 16 + lm;
      s16x4 vf = *(const s16x4*)(sVt + d * 256 + ((c8 ^ (d & 15)) << 2));
      accO[nt] = __builtin_amdgcn_mfma_f32_16x16x16bf16_1k(pf[tt], vf, accO[nt], 0, 0, 0);
    }
  }

  float invr[4];
#pragma unroll
  for (int r = 0; r < 4; ++r) invr[r] = __shfl(inv, lg * 4 + r, 64);

  const int tokbase = gb + i * 32 + jhalf * 16;
#pragma unroll
  for (int nt = 0; nt < 4; ++nt)
#pragma unroll
    for (int r = 0; r < 4; ++r) {
      int tok = tokbase + lg * 4 + r;
      aout[(size_t)tok * 768 + h * 64 + nt * 16 + lm] = f2bf(accO[nt][r] * invr[r]);
    }
}

// ---------------- launch ----------------
extern "C" void kernel_launch(void* const* d_in, const int* in_sizes, int n_in,
                              void* d_out, int out_size, void* d_ws, size_t ws_size,
                              hipStream_t stream) {
  const float* x      = (const float*)d_in[0];
  const float* qkv_w  = (const float*)d_in[1];
  const float* qkv_b  = (const float*)d_in[2];
  const float* proj_w = (const float*)d_in[3];
  const float* proj_b = (const float*)d_in[4];
  char* ws = (char*)d_ws;

  unsigned short* xb    = (unsigned short*)(ws);                 // 4096*768 bf16
  unsigned short* wqkv  = (unsigned short*)(ws + 6291456);       // 2304*768 bf16
  unsigned short* wproj = (unsigned short*)(ws + 9830400);       // 768*768 bf16
  unsigned short* qkvt  = (unsigned short*)(ws + 11010048);      // Q,K token-major + Vt
  unsigned short* attnb = (unsigned short*)(ws + 29884416);      // 4096*768 bf16
  unsigned short* vt    = qkvt + (size_t)24 * 4096 * 64;         // V transposed [12][64][4096]
  float* out = (float*)d_out;

  cvt_kernel<<<5376, 256, 0, stream>>>(x, qkv_w, proj_w, xb, wqkv, wproj);
  gemm_bt<2, 4, 0><<<dim3(18, 64), 256, 0, stream>>>(xb, wqkv, qkv_b, qkvt, vt, nullptr, 2304);
  natten_kernel<<<dim3(12, 16, 4), 256, 0, stream>>>(qkvt, attnb);
  gemm_bt<2, 2, 1><<<dim3(12, 64), 256, 0, stream>>>(attnb, wproj, proj_b, nullptr, nullptr, out, 768);
}

// Round 6
// 163.907 us; speedup vs baseline: 1.5581x; 1.5581x over previous
//
#include <hip/hip_runtime.h>

// B=4, HG=WG=32 -> 1024 tokens/batch, 4096 total; D=768, NH=12, HD=64, K=7 (49 neighbors)

typedef __bf16 bf16x8 __attribute__((ext_vector_type(8)));
typedef short s16x4 __attribute__((ext_vector_type(4)));
typedef float f32x4 __attribute__((ext_vector_type(4)));

__device__ __forceinline__ unsigned short f2bf(float f) {
  unsigned u = __float_as_uint(f);
  u += 0x7fffu + ((u >> 16) & 1u);   // RNE
  return (unsigned short)(u >> 16);
}

template <typename T>
__device__ __forceinline__ void gld_lds16(const T* g, T* l) {
  __builtin_amdgcn_global_load_lds((const __attribute__((address_space(1))) void*)g,
                                   (__attribute__((address_space(3))) void*)l, 16, 0, 0);
}

// ---------------- fp32 -> bf16 conversion of x, qkv_w, proj_w ----------------
__global__ void cvt_kernel(const float* __restrict__ x, const float* __restrict__ w1,
                           const float* __restrict__ w2, unsigned short* __restrict__ xo,
                           unsigned short* __restrict__ w1o, unsigned short* __restrict__ w2o) {
  const int n1 = 4096 * 768 / 4;
  const int n2 = 2304 * 768 / 4;
  const int n3 = 768 * 768 / 4;
  int i = blockIdx.x * 256 + threadIdx.x;
  float4 v;
  unsigned short* dst;
  int o;
  if (i < n1) {
    o = i; v = ((const float4*)x)[o]; dst = xo;
  } else if (i < n1 + n2) {
    o = i - n1; v = ((const float4*)w1)[o]; dst = w1o;
  } else if (i < n1 + n2 + n3) {
    o = i - n1 - n2; v = ((const float4*)w2)[o]; dst = w2o;
  } else {
    return;
  }
  ushort4 r;
  r.x = f2bf(v.x); r.y = f2bf(v.y); r.z = f2bf(v.z); r.w = f2bf(v.w);
  ((ushort4*)dst)[o] = r;
}

// ---------------- bf16 GEMM, C = A * B^T + bias ----------------
// R2's proven 2-barrier single-buffer K-loop, with (a) BM=64 for 2x blocks/CU
// and (b) slab-K-major LDS (16-row slabs, chunk-major) -> conflict-free ds_read_b128.
// Block tile: 64 x (NT*32). 4 waves in 2x2: wave tile 32 x (NT*16). BK=32, 24 iters.
// MODE 0 (qkv): Q cols scaled by 0.125*log2(e), token-major [h][4096][64];
//               K token-major; V TRANSPOSED vt[h][64][4096].
// MODE 1 (proj): fp32 out, row-major [M][N].
template <int NT, int MODE>
__global__ __launch_bounds__(256) void gemm_bt(const unsigned short* __restrict__ A,
                                               const unsigned short* __restrict__ Bm,
                                               const float* __restrict__ bias,
                                               unsigned short* __restrict__ obf,
                                               unsigned short* __restrict__ vtout,
                                               float* __restrict__ of32,
                                               int N) {
  constexpr int KD = 768;
  constexpr int SBW = NT / 2;              // B slabs staged per wave
  __shared__ __align__(16) unsigned short sA[64 * 32];        // 4 slabs x 512
  __shared__ __align__(16) unsigned short sB[NT * 32 * 32];   // 2*NT slabs x 512
  const int tid = threadIdx.x, lane = tid & 63, wv = tid >> 6;
  const int lr = lane & 15, lq = lane >> 4;
  const int m0 = blockIdx.y * 64;
  const int n0 = blockIdx.x * (NT * 32);

  // staging sources: slab s covers 16 rows; lane -> row (lane&15), k-chunk (lane>>4)
  const unsigned short* pA = A + (size_t)(m0 + wv * 16 + lr) * KD + lq * 8;
  const unsigned short* pB[SBW];
#pragma unroll
  for (int j = 0; j < SBW; ++j)
    pB[j] = Bm + (size_t)(n0 + (wv * SBW + j) * 16 + lr) * KD + lq * 8;

  f32x4 acc[2][NT] = {};

  for (int k0 = 0; k0 < KD; k0 += 32) {
    gld_lds16(pA + k0, sA + tid * 8);                      // slab wv
#pragma unroll
    for (int j = 0; j < SBW; ++j)
      gld_lds16(pB[j] + k0, sB + (wv * SBW + j) * 512 + lane * 8);
    __syncthreads();

    bf16x8 af[2], bfb[NT];
#pragma unroll
    for (int im = 0; im < 2; ++im)
      af[im] = *(const bf16x8*)(sA + ((wv >> 1) * 2 + im) * 512 + lq * 128 + lr * 8);
#pragma unroll
    for (int in = 0; in < NT; ++in)
      bfb[in] = *(const bf16x8*)(sB + ((wv & 1) * NT + in) * 512 + lq * 128 + lr * 8);
#pragma unroll
    for (int im = 0; im < 2; ++im)
#pragma unroll
      for (int in = 0; in < NT; ++in)
        acc[im][in] = __builtin_amdgcn_mfma_f32_16x16x32_bf16(af[im], bfb[in], acc[im][in], 0, 0, 0);
    __syncthreads();
  }

  const int mw = m0 + (wv >> 1) * 32;
  const int nw = n0 + (wv & 1) * (NT * 16);
#pragma unroll
  for (int im = 0; im < 2; ++im) {
#pragma unroll
    for (int in = 0; in < NT; ++in) {
      int gn = nw + in * 16 + lr;
      float bsv = bias[gn];
      if (MODE == 0) {
        int sidx = gn / 768;
        int rem = gn - sidx * 768;
        int hh = rem >> 6, dd = gn & 63;
        if (sidx == 2) {
          // V -> transposed vt[(hh*64+dd)*4096 + token]
          int gm0 = mw + im * 16 + lq * 4;
          ushort4 pk;
          pk.x = f2bf(acc[im][in][0] + bsv);
          pk.y = f2bf(acc[im][in][1] + bsv);
          pk.z = f2bf(acc[im][in][2] + bsv);
          pk.w = f2bf(acc[im][in][3] + bsv);
          *(ushort4*)(vtout + (size_t)(hh * 64 + dd) * 4096 + gm0) = pk;
        } else {
          const float scale = (sidx == 0) ? 0.18033688f : 1.0f;  // 0.125 * log2(e) for Q
#pragma unroll
          for (int r = 0; r < 4; ++r) {
            int gm = mw + im * 16 + lq * 4 + r;
            obf[((size_t)(sidx * 12 + hh) * 4096 + gm) * 64 + dd] = f2bf((acc[im][in][r] + bsv) * scale);
          }
        }
      } else {
#pragma unroll
        for (int r = 0; r < 4; ++r) {
          int gm = mw + im * 16 + lq * 4 + r;
          of32[(size_t)gm * N + gn] = acc[im][in][r] + bsv;
        }
      }
    }
  }
}

// ---------------- neighborhood attention (MFMA) ---------------- (unchanged)
__global__ __launch_bounds__(256, 2) void natten_kernel(const unsigned short* __restrict__ qkvt,
                                                        unsigned short* __restrict__ aout) {
  __shared__ __align__(16) unsigned short sQ[64 * 64];    //  8 KB
  __shared__ __align__(16) unsigned short sK[256 * 64];   // 32 KB
  __shared__ __align__(16) unsigned short sVt[64 * 256];  // 32 KB
  const int h = blockIdx.x, ip = blockIdx.y, b = blockIdx.z;
  const int i0 = ip * 2;
  const int tid = threadIdx.x, lane = tid & 63, wv = tid >> 6;
  const int lg = lane >> 4, lm = lane & 15;
  int si0 = i0 - 3; si0 = si0 < 0 ? 0 : si0; if (si0 > 25) si0 = 25;
  const int gb = b * 1024;
  const unsigned short* Qg = qkvt + ((size_t)h * 4096 + gb + i0 * 32) * 64;
  const unsigned short* Kg = qkvt + ((size_t)(12 + h) * 4096 + gb) * 64;
  const unsigned short* Vg = qkvt + (size_t)24 * 4096 * 64 + (size_t)h * 64 * 4096 + gb;

#pragma unroll
  for (int it = 0; it < 2; ++it) {  // Q: 64 q x 64 d
    int f = it * 256 + tid;
    int q = f >> 3, c16 = f & 7;
    uint4 v = *(const uint4*)(Qg + q * 64 + c16 * 8);
    int s = q & 15;
    *(uint2*)(sQ + q * 64 + ((((c16 << 1)) ^ s) << 2)) = make_uint2(v.x, v.y);
    *(uint2*)(sQ + q * 64 + ((((c16 << 1) | 1) ^ s) << 2)) = make_uint2(v.z, v.w);
  }
#pragma unroll
  for (int it = 0; it < 8; ++it) {  // K: 256 tok x 64 d
    int f = it * 256 + tid;
    int t = f >> 3, c16 = f & 7;
    int wr = t >> 5, c = t & 31;
    int row = si0 + wr; if (row > 31) row = 31;
    uint4 v = *(const uint4*)(Kg + (row * 32 + c) * 64 + c16 * 8);
    int s = t & 15;
    *(uint2*)(sK + t * 64 + ((((c16 << 1)) ^ s) << 2)) = make_uint2(v.x, v.y);
    *(uint2*)(sK + t * 64 + ((((c16 << 1) | 1) ^ s) << 2)) = make_uint2(v.z, v.w);
  }
#pragma unroll
  for (int it = 0; it < 8; ++it) {  // Vt: 64 d x 256 tok
    int f = it * 256 + tid;
    int d = f >> 5, tc16 = f & 31;
    int wr = tc16 >> 2;
    int row = si0 + wr; if (row > 31) row = 31;
    uint4 v = *(const uint4*)(Vg + (size_t)d * 4096 + row * 32 + (tc16 & 3) * 8);
    int s = d & 15;
    *(uint2*)(sVt + d * 256 + ((((tc16 << 1)) ^ s) << 2)) = make_uint2(v.x, v.y);
    *(uint2*)(sVt + d * 256 + ((((tc16 << 1) | 1) ^ s) << 2)) = make_uint2(v.z, v.w);
  }
  __syncthreads();

  const int row_sel = wv >> 1;
  const int jhalf = wv & 1;
  const int i = i0 + row_sel;
  int si_w = i - 3; si_w = si_w < 0 ? 0 : si_w; if (si_w > 25) si_w = 25;
  const int toff = (si_w - si0) * 32;
  const int j = jhalf * 16 + lm;
  int sj = j - 3; sj = sj < 0 ? 0 : sj; if (sj > 25) sj = 25;

  float madd[2][4];
#pragma unroll
  for (int p = 0; p < 2; ++p)
#pragma unroll
    for (int r = 0; r < 4; ++r) {
      int c = p * 16 + lg * 4 + r;
      madd[p][r] = (c >= sj && c <= sj + 6) ? 0.f : -1e30f;
    }

  s16x4 qf[4];
  const int qrow = row_sel * 32 + j;
#pragma unroll
  for (int ks = 0; ks < 4; ++ks)
    qf[ks] = *(const s16x4*)(sQ + qrow * 64 + ((((ks << 2) + lg) ^ (qrow & 15)) << 2));

  f32x4 accS[14];
#pragma unroll
  for (int tt = 0; tt < 14; ++tt) {
    f32x4 a = {0.f, 0.f, 0.f, 0.f};
    const int trow = toff + tt * 16 + lm;
    const unsigned short* kr = sK + trow * 64;
    const int sw = trow & 15;
#pragma unroll
    for (int ks = 0; ks < 4; ++ks) {
      s16x4 kf = *(const s16x4*)(kr + ((((ks << 2) + lg) ^ sw) << 2));
      a = __builtin_amdgcn_mfma_f32_16x16x16bf16_1k(kf, qf[ks], a, 0, 0, 0);
    }
    accS[tt] = a;
  }

  float mx = -3e38f;
#pragma unroll
  for (int tt = 0; tt < 14; ++tt)
#pragma unroll
    for (int r = 0; r < 4; ++r) {
      float v = accS[tt][r] + madd[tt & 1][r];
      accS[tt][r] = v;
      mx = fmaxf(mx, v);
    }
  mx = fmaxf(mx, __shfl_xor(mx, 16, 64));
  mx = fmaxf(mx, __shfl_xor(mx, 32, 64));
  float sum = 0.f;
#pragma unroll
  for (int tt = 0; tt < 14; ++tt)
#pragma unroll
    for (int r = 0; r < 4; ++r) {
      float p = exp2f(accS[tt][r] - mx);
      accS[tt][r] = p;
      sum += p;
    }
  sum += __shfl_xor(sum, 16, 64);
  sum += __shfl_xor(sum, 32, 64);
  const float inv = 1.f / sum;

  s16x4 pf[14];
#pragma unroll
  for (int tt = 0; tt < 14; ++tt) {
    union { unsigned u[2]; s16x4 v; } pk;
    pk.u[0] = ((unsigned)f2bf(accS[tt][1]) << 16) | f2bf(accS[tt][0]);
    pk.u[1] = ((unsigned)f2bf(accS[tt][3]) << 16) | f2bf(accS[tt][2]);
    pf[tt] = pk.v;
  }

  f32x4 accO[4] = {};
  const int choff = toff >> 2;
#pragma unroll
  for (int tt = 0; tt < 14; ++tt) {
    const int c8 = choff + tt * 4 + lg;
#pragma unroll
    for (int nt = 0; nt < 4; ++nt) {
      const int d = nt * 16 + lm;
      s16x4 vf = *(const s16x4*)(sVt + d * 256 + ((c8 ^ (d & 15)) << 2));
      accO[nt] = __builtin_amdgcn_mfma_f32_16x16x16bf16_1k(pf[tt], vf, accO[nt], 0, 0, 0);
    }
  }

  float invr[4];
#pragma unroll
  for (int r = 0; r < 4; ++r) invr[r] = __shfl(inv, lg * 4 + r, 64);

  const int tokbase = gb + i * 32 + jhalf * 16;
#pragma unroll
  for (int nt = 0; nt < 4; ++nt)
#pragma unroll
    for (int r = 0; r < 4; ++r) {
      int tok = tokbase + lg * 4 + r;
      aout[(size_t)tok * 768 + h * 64 + nt * 16 + lm] = f2bf(accO[nt][r] * invr[r]);
    }
}

// ---------------- launch ----------------
extern "C" void kernel_launch(void* const* d_in, const int* in_sizes, int n_in,
                              void* d_out, int out_size, void* d_ws, size_t ws_size,
                              hipStream_t stream) {
  const float* x      = (const float*)d_in[0];
  const float* qkv_w  = (const float*)d_in[1];
  const float* qkv_b  = (const float*)d_in[2];
  const float* proj_w = (const float*)d_in[3];
  const float* proj_b = (const float*)d_in[4];
  char* ws = (char*)d_ws;

  unsigned short* xb    = (unsigned short*)(ws);                 // 4096*768 bf16
  unsigned short* wqkv  = (unsigned short*)(ws + 6291456);       // 2304*768 bf16
  unsigned short* wproj = (unsigned short*)(ws + 9830400);       // 768*768 bf16
  unsigned short* qkvt  = (unsigned short*)(ws + 11010048);      // Q,K token-major + Vt
  unsigned short* attnb = (unsigned short*)(ws + 29884416);      // 4096*768 bf16
  unsigned short* vt    = qkvt + (size_t)24 * 4096 * 64;         // V transposed [12][64][4096]
  float* out = (float*)d_out;

  cvt_kernel<<<5376, 256, 0, stream>>>(x, qkv_w, proj_w, xb, wqkv, wproj);
  gemm_bt<4, 0><<<dim3(18, 64), 256, 0, stream>>>(xb, wqkv, qkv_b, qkvt, vt, nullptr, 2304);
  natten_kernel<<<dim3(12, 16, 4), 256, 0, stream>>>(qkvt, attnb);
  gemm_bt<2, 1><<<dim3(12, 64), 256, 0, stream>>>(attnb, wproj, proj_b, nullptr, nullptr, out, 768);
}

// Round 7
// 156.828 us; speedup vs baseline: 1.6285x; 1.0451x over previous
//
#include <hip/hip_runtime.h>

// B=4, HG=WG=32 -> 1024 tokens/batch, 4096 total; D=768, NH=12, HD=64, K=7 (49 neighbors)

typedef __bf16 bf16x8 __attribute__((ext_vector_type(8)));
typedef short s16x4 __attribute__((ext_vector_type(4)));
typedef float f32x4 __attribute__((ext_vector_type(4)));

__device__ __forceinline__ unsigned short f2bf(float f) {
  unsigned u = __float_as_uint(f);
  u += 0x7fffu + ((u >> 16) & 1u);   // RNE
  return (unsigned short)(u >> 16);
}

template <typename T>
__device__ __forceinline__ void gld_lds16(const T* g, T* l) {
  __builtin_amdgcn_global_load_lds((const __attribute__((address_space(1))) void*)g,
                                   (__attribute__((address_space(3))) void*)l, 16, 0, 0);
}

// s_waitcnt immediates (gfx9 encoding: vm[3:0]|exp[6:4]|lgkm[11:8]|vm_hi[15:14])
#define WAIT_VM6   __builtin_amdgcn_s_waitcnt(0x0F76)  // vmcnt(6), lgkm/exp no-wait
#define WAIT_VM0   __builtin_amdgcn_s_waitcnt(0x0F70)  // vmcnt(0)
#define WAIT_LGKM0 __builtin_amdgcn_s_waitcnt(0xC07F)  // lgkmcnt(0), vm/exp no-wait

// ---------------- fp32 -> bf16 conversion of x, qkv_w, proj_w ----------------
__global__ void cvt_kernel(const float* __restrict__ x, const float* __restrict__ w1,
                           const float* __restrict__ w2, unsigned short* __restrict__ xo,
                           unsigned short* __restrict__ w1o, unsigned short* __restrict__ w2o) {
  const int n1 = 4096 * 768 / 4;
  const int n2 = 2304 * 768 / 4;
  const int n3 = 768 * 768 / 4;
  int i = blockIdx.x * 256 + threadIdx.x;
  float4 v;
  unsigned short* dst;
  int o;
  if (i < n1) {
    o = i; v = ((const float4*)x)[o]; dst = xo;
  } else if (i < n1 + n2) {
    o = i - n1; v = ((const float4*)w1)[o]; dst = w1o;
  } else if (i < n1 + n2 + n3) {
    o = i - n1 - n2; v = ((const float4*)w2)[o]; dst = w2o;
  } else {
    return;
  }
  ushort4 r;
  r.x = f2bf(v.x); r.y = f2bf(v.y); r.z = f2bf(v.z); r.w = f2bf(v.w);
  ((ushort4*)dst)[o] = r;
}

// ---------------- bf16 GEMM, C = A * B^T + bias  (software-pipelined) ----------------
// Raw s_barrier + hand-placed vmcnt(N): the staging queue is NEVER drained to zero;
// tile it+2 stays in flight across the barrier while tile it+1 is consumed.
// BM=64, BN=128, BK=64, double-buffered LDS (48 KB), slab-K-major (conflict-free).
// Per iteration: 12 ds_read_b128 + 6 global_load_lds(16B) + 16 MFMA.
// MODE 0 (qkv): Q cols scaled by 0.125*log2(e), token-major [h][4096][64];
//               K token-major; V TRANSPOSED vt[h][64][4096].
// MODE 1 (proj): fp32 out, row-major [M][N].
template <int MODE>
__global__ __launch_bounds__(256) void gemm_pipe(const unsigned short* __restrict__ A,
                                                 const unsigned short* __restrict__ Bm,
                                                 const float* __restrict__ bias,
                                                 unsigned short* __restrict__ obf,
                                                 unsigned short* __restrict__ vtout,
                                                 float* __restrict__ of32,
                                                 int N) {
  constexpr int KD = 768, NITER = 12;
  __shared__ __align__(16) unsigned short sA[2 * 4096];   // 2 x 64x64
  __shared__ __align__(16) unsigned short sB[2 * 8192];   // 2 x 128x64
  const int tid = threadIdx.x, lane = tid & 63, wv = tid >> 6;
  const int lr = lane & 15, lq = lane >> 4;
  const int m0 = blockIdx.y * 64, n0 = blockIdx.x * 128;

  // staging: wave wv owns A-slab wv and B-slabs {2wv, 2wv+1}; lane -> row lr, k-chunk lq
  const unsigned short* gA  = A  + (size_t)(m0 + wv * 16 + lr) * KD + lq * 8;
  const unsigned short* gB0 = Bm + (size_t)(n0 + (wv * 2) * 16 + lr) * KD + lq * 8;
  const unsigned short* gB1 = Bm + (size_t)(n0 + (wv * 2 + 1) * 16 + lr) * KD + lq * 8;
  unsigned short* lA  = sA + wv * 1024 + lane * 8;
  unsigned short* lB0 = sB + (wv * 2) * 1024 + lane * 8;
  unsigned short* lB1 = sB + (wv * 2 + 1) * 1024 + lane * 8;

  auto stage = [&](int it, int bsel) {
    const int k0 = it * 64;
    gld_lds16(gA + k0,       lA + bsel * 4096);
    gld_lds16(gA + k0 + 32,  lA + bsel * 4096 + 512);
    gld_lds16(gB0 + k0,      lB0 + bsel * 8192);
    gld_lds16(gB0 + k0 + 32, lB0 + bsel * 8192 + 512);
    gld_lds16(gB1 + k0,      lB1 + bsel * 8192);
    gld_lds16(gB1 + k0 + 32, lB1 + bsel * 8192 + 512);
  };

  f32x4 acc[2][4] = {};

  stage(0, 0);
  stage(1, 1);
  WAIT_VM6;                          // tile 0 landed (tile 1 still in flight)
  __builtin_amdgcn_s_barrier();

#pragma unroll
  for (int it = 0; it < NITER; ++it) {
    const int cur = it & 1;
    // fragment reads (slab-K-major: each 16-lane group reads contiguous 256B)
    const unsigned short* bA = sA + cur * 4096 + ((wv >> 1) * 2) * 1024 + lq * 128 + lr * 8;
    const unsigned short* bB = sB + cur * 8192 + ((wv & 1) * 4) * 1024 + lq * 128 + lr * 8;
    bf16x8 af[2][2], bfb[2][4];
#pragma unroll
    for (int c = 0; c < 2; ++c) {
#pragma unroll
      for (int im = 0; im < 2; ++im)
        af[c][im] = *(const bf16x8*)(bA + im * 1024 + c * 512);
#pragma unroll
      for (int in = 0; in < 4; ++in)
        bfb[c][in] = *(const bf16x8*)(bB + in * 1024 + c * 512);
    }
    WAIT_LGKM0;                      // frags in VGPRs (wave-local, fast)
    __builtin_amdgcn_s_barrier();    // all waves done reading buf cur -> safe to overwrite
    if (it + 2 < NITER) stage(it + 2, cur);
#pragma unroll
    for (int c = 0; c < 2; ++c)
#pragma unroll
      for (int im = 0; im < 2; ++im)
#pragma unroll
        for (int in = 0; in < 4; ++in)
          acc[im][in] = __builtin_amdgcn_mfma_f32_16x16x32_bf16(af[c][im], bfb[c][in], acc[im][in], 0, 0, 0);
    if (it + 1 < NITER) {
      if (it + 2 < NITER) WAIT_VM6;  // tile it+1 landed; tile it+2 still flying
      else                WAIT_VM0;  // tail: drain last tile
      __builtin_amdgcn_s_barrier();
    }
  }

  const int mw = m0 + (wv >> 1) * 32;
  const int nw = n0 + (wv & 1) * 64;
#pragma unroll
  for (int im = 0; im < 2; ++im) {
#pragma unroll
    for (int in = 0; in < 4; ++in) {
      int gn = nw + in * 16 + lr;
      float bsv = bias[gn];
      if (MODE == 0) {
        int sidx = gn / 768;
        int rem = gn - sidx * 768;
        int hh = rem >> 6, dd = gn & 63;
        if (sidx == 2) {
          // V -> transposed vt[(hh*64+dd)*4096 + token]
          int gm0 = mw + im * 16 + lq * 4;
          ushort4 pk;
          pk.x = f2bf(acc[im][in][0] + bsv);
          pk.y = f2bf(acc[im][in][1] + bsv);
          pk.z = f2bf(acc[im][in][2] + bsv);
          pk.w = f2bf(acc[im][in][3] + bsv);
          *(ushort4*)(vtout + (size_t)(hh * 64 + dd) * 4096 + gm0) = pk;
        } else {
          const float scale = (sidx == 0) ? 0.18033688f : 1.0f;  // 0.125 * log2(e) for Q
#pragma unroll
          for (int r = 0; r < 4; ++r) {
            int gm = mw + im * 16 + lq * 4 + r;
            obf[((size_t)(sidx * 12 + hh) * 4096 + gm) * 64 + dd] = f2bf((acc[im][in][r] + bsv) * scale);
          }
        }
      } else {
#pragma unroll
        for (int r = 0; r < 4; ++r) {
          int gm = mw + im * 16 + lq * 4 + r;
          of32[(size_t)gm * N + gn] = acc[im][in][r] + bsv;
        }
      }
    }
  }
}

// ---------------- neighborhood attention (MFMA) ---------------- (unchanged)
__global__ __launch_bounds__(256, 2) void natten_kernel(const unsigned short* __restrict__ qkvt,
                                                        unsigned short* __restrict__ aout) {
  __shared__ __align__(16) unsigned short sQ[64 * 64];    //  8 KB
  __shared__ __align__(16) unsigned short sK[256 * 64];   // 32 KB
  __shared__ __align__(16) unsigned short sVt[64 * 256];  // 32 KB
  const int h = blockIdx.x, ip = blockIdx.y, b = blockIdx.z;
  const int i0 = ip * 2;
  const int tid = threadIdx.x, lane = tid & 63, wv = tid >> 6;
  const int lg = lane >> 4, lm = lane & 15;
  int si0 = i0 - 3; si0 = si0 < 0 ? 0 : si0; if (si0 > 25) si0 = 25;
  const int gb = b * 1024;
  const unsigned short* Qg = qkvt + ((size_t)h * 4096 + gb + i0 * 32) * 64;
  const unsigned short* Kg = qkvt + ((size_t)(12 + h) * 4096 + gb) * 64;
  const unsigned short* Vg = qkvt + (size_t)24 * 4096 * 64 + (size_t)h * 64 * 4096 + gb;

#pragma unroll
  for (int it = 0; it < 2; ++it) {  // Q: 64 q x 64 d
    int f = it * 256 + tid;
    int q = f >> 3, c16 = f & 7;
    uint4 v = *(const uint4*)(Qg + q * 64 + c16 * 8);
    int s = q & 15;
    *(uint2*)(sQ + q * 64 + ((((c16 << 1)) ^ s) << 2)) = make_uint2(v.x, v.y);
    *(uint2*)(sQ + q * 64 + ((((c16 << 1) | 1) ^ s) << 2)) = make_uint2(v.z, v.w);
  }
#pragma unroll
  for (int it = 0; it < 8; ++it) {  // K: 256 tok x 64 d
    int f = it * 256 + tid;
    int t = f >> 3, c16 = f & 7;
    int wr = t >> 5, c = t & 31;
    int row = si0 + wr; if (row > 31) row = 31;
    uint4 v = *(const uint4*)(Kg + (row * 32 + c) * 64 + c16 * 8);
    int s = t & 15;
    *(uint2*)(sK + t * 64 + ((((c16 << 1)) ^ s) << 2)) = make_uint2(v.x, v.y);
    *(uint2*)(sK + t * 64 + ((((c16 << 1) | 1) ^ s) << 2)) = make_uint2(v.z, v.w);
  }
#pragma unroll
  for (int it = 0; it < 8; ++it) {  // Vt: 64 d x 256 tok
    int f = it * 256 + tid;
    int d = f >> 5, tc16 = f & 31;
    int wr = tc16 >> 2;
    int row = si0 + wr; if (row > 31) row = 31;
    uint4 v = *(const uint4*)(Vg + (size_t)d * 4096 + row * 32 + (tc16 & 3) * 8);
    int s = d & 15;
    *(uint2*)(sVt + d * 256 + ((((tc16 << 1)) ^ s) << 2)) = make_uint2(v.x, v.y);
    *(uint2*)(sVt + d * 256 + ((((tc16 << 1) | 1) ^ s) << 2)) = make_uint2(v.z, v.w);
  }
  __syncthreads();

  const int row_sel = wv >> 1;
  const int jhalf = wv & 1;
  const int i = i0 + row_sel;
  int si_w = i - 3; si_w = si_w < 0 ? 0 : si_w; if (si_w > 25) si_w = 25;
  const int toff = (si_w - si0) * 32;
  const int j = jhalf * 16 + lm;
  int sj = j - 3; sj = sj < 0 ? 0 : sj; if (sj > 25) sj = 25;

  float madd[2][4];
#pragma unroll
  for (int p = 0; p < 2; ++p)
#pragma unroll
    for (int r = 0; r < 4; ++r) {
      int c = p * 16 + lg * 4 + r;
      madd[p][r] = (c >= sj && c <= sj + 6) ? 0.f : -1e30f;
    }

  s16x4 qf[4];
  const int qrow = row_sel * 32 + j;
#pragma unroll
  for (int ks = 0; ks < 4; ++ks)
    qf[ks] = *(const s16x4*)(sQ + qrow * 64 + ((((ks << 2) + lg) ^ (qrow & 15)) << 2));

  f32x4 accS[14];
#pragma unroll
  for (int tt = 0; tt < 14; ++tt) {
    f32x4 a = {0.f, 0.f, 0.f, 0.f};
    const int trow = toff + tt * 16 + lm;
    const unsigned short* kr = sK + trow * 64;
    const int sw = trow & 15;
#pragma unroll
    for (int ks = 0; ks < 4; ++ks) {
      s16x4 kf = *(const s16x4*)(kr + ((((ks << 2) + lg) ^ sw) << 2));
      a = __builtin_amdgcn_mfma_f32_16x16x16bf16_1k(kf, qf[ks], a, 0, 0, 0);
    }
    accS[tt] = a;
  }

  float mx = -3e38f;
#pragma unroll
  for (int tt = 0; tt < 14; ++tt)
#pragma unroll
    for (int r = 0; r < 4; ++r) {
      float v = accS[tt][r] + madd[tt & 1][r];
      accS[tt][r] = v;
      mx = fmaxf(mx, v);
    }
  mx = fmaxf(mx, __shfl_xor(mx, 16, 64));
  mx = fmaxf(mx, __shfl_xor(mx, 32, 64));
  float sum = 0.f;
#pragma unroll
  for (int tt = 0; tt < 14; ++tt)
#pragma unroll
    for (int r = 0; r < 4; ++r) {
      float p = exp2f(accS[tt][r] - mx);
      accS[tt][r] = p;
      sum += p;
    }
  sum += __shfl_xor(sum, 16, 64);
  sum += __shfl_xor(sum, 32, 64);
  const float inv = 1.f / sum;

  s16x4 pf[14];
#pragma unroll
  for (int tt = 0; tt < 14; ++tt) {
    union { unsigned u[2]; s16x4 v; } pk;
    pk.u[0] = ((unsigned)f2bf(accS[tt][1]) << 16) | f2bf(accS[tt][0]);
    pk.u[1] = ((unsigned)f2bf(accS[tt][3]) << 16) | f2bf(accS[tt][2]);
    pf[tt] = pk.v;
  }

  f32x4 accO[4] = {};
  const int choff = toff >> 2;
#pragma unroll
  for (int tt = 0; tt < 14; ++tt) {
    const int c8 = choff + tt * 4 + lg;
#pragma unroll
    for (int nt = 0; nt < 4; ++nt) {
      const int d = nt * 16 + lm;
      s16x4 vf = *(const s16x4*)(sVt + d * 256 + ((c8 ^ (d & 15)) << 2));
      accO[nt] = __builtin_amdgcn_mfma_f32_16x16x16bf16_1k(pf[tt], vf, accO[nt], 0, 0, 0);
    }
  }

  float invr[4];
#pragma unroll
  for (int r = 0; r < 4; ++r) invr[r] = __shfl(inv, lg * 4 + r, 64);

  const int tokbase = gb + i * 32 + jhalf * 16;
#pragma unroll
  for (int nt = 0; nt < 4; ++nt)
#pragma unroll
    for (int r = 0; r < 4; ++r) {
      int tok = tokbase + lg * 4 + r;
      aout[(size_t)tok * 768 + h * 64 + nt * 16 + lm] = f2bf(accO[nt][r] * invr[r]);
    }
}

// ---------------- launch ----------------
extern "C" void kernel_launch(void* const* d_in, const int* in_sizes, int n_in,
                              void* d_out, int out_size, void* d_ws, size_t ws_size,
                              hipStream_t stream) {
  const float* x      = (const float*)d_in[0];
  const float* qkv_w  = (const float*)d_in[1];
  const float* qkv_b  = (const float*)d_in[2];
  const float* proj_w = (const float*)d_in[3];
  const float* proj_b = (const float*)d_in[4];
  char* ws = (char*)d_ws;

  unsigned short* xb    = (unsigned short*)(ws);                 // 4096*768 bf16
  unsigned short* wqkv  = (unsigned short*)(ws + 6291456);       // 2304*768 bf16
  unsigned short* wproj = (unsigned short*)(ws + 9830400);       // 768*768 bf16
  unsigned short* qkvt  = (unsigned short*)(ws + 11010048);      // Q,K token-major + Vt
  unsigned short* attnb = (unsigned short*)(ws + 29884416);      // 4096*768 bf16
  unsigned short* vt    = qkvt + (size_t)24 * 4096 * 64;         // V transposed [12][64][4096]
  float* out = (float*)d_out;

  cvt_kernel<<<5376, 256, 0, stream>>>(x, qkv_w, proj_w, xb, wqkv, wproj);
  gemm_pipe<0><<<dim3(18, 64), 256, 0, stream>>>(xb, wqkv, qkv_b, qkvt, vt, nullptr, 2304);
  natten_kernel<<<dim3(12, 16, 4), 256, 0, stream>>>(qkvt, attnb);
  gemm_pipe<1><<<dim3(6, 64), 256, 0, stream>>>(attnb, wproj, proj_b, nullptr, nullptr, out, 768);
}